// Round 7
// baseline (750.912 us; speedup 1.0000x reference)
//
#include <hip/hip_runtime.h>
#include <math.h>

#define HD   128
#define HD2  256
#define LN_EPS 1e-5f
#define BM 64
#define PT 264   // LDS pitch in bf16 elems (256 + 8 pad)

typedef __attribute__((ext_vector_type(8))) short s8v;    // 8 x bf16 (4 VGPR)
typedef __attribute__((ext_vector_type(4))) float f4v;    // MFMA acc

static __device__ __forceinline__ float waveReduceSum(float v) {
#pragma unroll
  for (int off = 32; off >= 1; off >>= 1) v += __shfl_xor(v, off);
  return v;
}

static __device__ __forceinline__ float bf2f(unsigned short u) {
  union { unsigned int i; float f; } c; c.i = ((unsigned int)u) << 16; return c.f;
}

static __device__ __forceinline__ unsigned short f2bf(float f) {
  union { float f; unsigned int i; } c; c.f = f;
  unsigned int lsb = (c.i >> 16) & 1u;
  return (unsigned short)((c.i + 0x7fffu + lsb) >> 16);
}

// ---------------- CSR build ----------------
__global__ void k_izero(int* __restrict__ p, int n) {
  int i = blockIdx.x * blockDim.x + threadIdx.x;
  if (i < n) p[i] = 0;
}

// all 4 degree counts in one pass
__global__ void k_icount4(const int* __restrict__ i0, const int* __restrict__ i1,
                          const int* __restrict__ i2, const int* __restrict__ i3,
                          int* __restrict__ degbase, int N, int e1, int e2, int e3) {
  int i = blockIdx.x * blockDim.x + threadIdx.x;
  if (i < e1) atomicAdd(&degbase[i0[i]], 1);
  if (i < e2) atomicAdd(&degbase[N + i1[i]], 1);
  if (i < e3) atomicAdd(&degbase[2 * N + i2[i]], 1);
  if (i < e3) atomicAdd(&degbase[3 * N + i3[i]], 1);
}

__global__ void k_norms(const int* __restrict__ cs, const int* __restrict__ cd,
                        const int* __restrict__ chn, const int* __restrict__ che,
                        float* __restrict__ dsoc, float* __restrict__ ddif,
                        float* __restrict__ Dinv, float* __restrict__ Binv, int n) {
  int i = blockIdx.x * blockDim.x + threadIdx.x;
  if (i >= n) return;
  dsoc[i] = rsqrtf((float)(cs[i] + 1));
  ddif[i] = rsqrtf((float)(cd[i] + 1));
  int dn = chn[i]; Dinv[i] = dn > 0 ? 1.0f / (float)dn : 0.0f;
  int bh = che[i]; Binv[i] = bh > 0 ? 1.0f / (float)bh : 0.0f;
}

// grid (NB, 4): per-graph block sums
__global__ __launch_bounds__(256) void k_bsum(const int* __restrict__ degbase,
                                              int* __restrict__ bsumbase, int n) {
  __shared__ int sh[256];
  const int* deg = degbase + (size_t)blockIdx.y * n;
  int* bsum = bsumbase + blockIdx.y * 1024;
  int t = threadIdx.x;
  int i = blockIdx.x * 256 + t;
  sh[t] = (i < n) ? deg[i] : 0;
  __syncthreads();
  for (int d = 128; d > 0; d >>= 1) { if (t < d) sh[t] += sh[t + d]; __syncthreads(); }
  if (t == 0) bsum[blockIdx.x] = sh[0];
}

// grid (1, 4)
__global__ __launch_bounds__(1024) void k_scanblk(const int* __restrict__ bsumbase,
                                                  int* __restrict__ bbasebase, int nb) {
  __shared__ int sh[1024];
  const int* bsum = bsumbase + blockIdx.y * 1024;
  int* bbase = bbasebase + blockIdx.y * 1024;
  int t = threadIdx.x;
  int v = (t < nb) ? bsum[t] : 0;
  sh[t] = v;
  __syncthreads();
  for (int d = 1; d < 1024; d <<= 1) {
    int x = (t >= d) ? sh[t - d] : 0;
    __syncthreads();
    sh[t] += x;
    __syncthreads();
  }
  if (t < nb) bbase[t] = sh[t] - v;   // exclusive
}

// grid (NB, 4)
__global__ __launch_bounds__(256) void k_fillof(const int* __restrict__ degbase,
                                                const int* __restrict__ bbasebase,
                                                int* __restrict__ offbase, int* __restrict__ curbase,
                                                int n) {
  __shared__ int sh[256];
  const int* deg = degbase + (size_t)blockIdx.y * n;
  const int* bbase = bbasebase + blockIdx.y * 1024;
  int* off = offbase + (size_t)blockIdx.y * n;
  int* cur = curbase + (size_t)blockIdx.y * n;
  int t = threadIdx.x;
  int i = blockIdx.x * 256 + t;
  int v = (i < n) ? deg[i] : 0;
  sh[t] = v;
  __syncthreads();
  for (int d = 1; d < 256; d <<= 1) {
    int x = (t >= d) ? sh[t - d] : 0;
    __syncthreads();
    sh[t] += x;
    __syncthreads();
  }
  if (i < n) { int e = bbase[blockIdx.x] + sh[t] - v; off[i] = e; cur[i] = e; }
}

// all 4 CSR column fills in one pass
__global__ void k_fillcol4(
    const int* __restrict__ s0, const int* __restrict__ d0, int* __restrict__ c0, int* __restrict__ v0,
    const int* __restrict__ s1, const int* __restrict__ d1, int* __restrict__ c1, int* __restrict__ v1,
    const int* __restrict__ s2, const int* __restrict__ d2, int* __restrict__ c2, int* __restrict__ v2,
    const int* __restrict__ s3, const int* __restrict__ d3, int* __restrict__ c3, int* __restrict__ v3,
    int e1, int e2, int e3) {
  int i = blockIdx.x * blockDim.x + threadIdx.x;
  if (i < e1) { int d = d0[i]; v0[atomicAdd(&c0[d], 1)] = s0[i]; }
  if (i < e2) { int d = d1[i]; v1[atomicAdd(&c1[d], 1)] = s1[i]; }
  if (i < e3) { int d = d2[i]; v2[atomicAdd(&c2[d], 1)] = s2[i]; }
  if (i < e3) { int d = d3[i]; v3[atomicAdd(&c3[d], 1)] = s3[i]; }
}

// fp32 -> bf16 bulk convert (vectorized)
__global__ void k_cvt(const float* __restrict__ in, unsigned short* __restrict__ out, int n4) {
  int i = blockIdx.x * blockDim.x + threadIdx.x;
  if (i < n4) {
    float4 v = reinterpret_cast<const float4*>(in)[i];
    ushort4 o;
    o.x = f2bf(v.x); o.y = f2bf(v.y); o.z = f2bf(v.z); o.w = f2bf(v.w);
    reinterpret_cast<ushort4*>(out)[i] = o;
  }
}

// W [K][NC] fp32 -> fragment-ordered bf16
__global__ void k_wfrag(const float* __restrict__ W, unsigned short* __restrict__ Wf,
                        int KT, int NC, int total) {
  int t = blockIdx.x * blockDim.x + threadIdx.x;
  if (t >= total) return;
  int l = t & 63;
  int rest = t >> 6;
  int kt = rest % KT, ct = rest / KT;
  int col = ct * 16 + (l & 15);
  int k0 = kt * 32 + (l >> 4) * 8;
  s8v v;
#pragma unroll
  for (int b = 0; b < 8; ++b) v[b] = (short)f2bf(W[(size_t)(k0 + b) * NC + col]);
  *reinterpret_cast<s8v*>(&Wf[(size_t)t * 8]) = v;
}

// ---------------- gather: 8 rows per wave, interleaved edge chains ----------------
// acc[d] = selfterm + sum_{j in CSR[d]} sscale[col_j] * src[col_j]
// LNEPI 0: out = bf16(acc * dscale[d])
// LNEPI 1: out = bf16( LN(relu(acc*dscale + lnb)) * lng + lnbe )
// LNEPI 2: same but f32 out
template <int LNEPI>
__global__ __launch_bounds__(256) void k_gather8(
    const unsigned short* __restrict__ src, const float* __restrict__ sscale,
    const float* __restrict__ selfs, int selfmode, const float* __restrict__ dscale,
    const int* __restrict__ off, const int* __restrict__ endp,
    const int* __restrict__ colv,
    const float* __restrict__ lnb, const float* __restrict__ lng,
    const float* __restrict__ lnbe, void* __restrict__ outp, int n) {
  int tid = threadIdx.x;
  int w = tid >> 6, l = tid & 63;
  int row0 = blockIdx.x * 32 + w * 8;
  const ushort2* s2 = reinterpret_cast<const ushort2*>(src);
  float ax[8], ay[8];
  int jj[8], ee[8];
#pragma unroll
  for (int r = 0; r < 8; ++r) {
    int row = row0 + r;
    bool v = row < n;
    jj[r] = v ? off[row] : 0;
    ee[r] = v ? endp[row] : 0;
    ax[r] = 0.f; ay[r] = 0.f;
    if (selfmode && v) {
      float ss = (selfmode == 2) ? selfs[row] : 1.0f;
      ushort2 u = s2[(size_t)row * 64 + l];
      ax[r] = bf2f(u.x) * ss; ay[r] = bf2f(u.y) * ss;
    }
  }
  while (true) {
    bool a[8];
    bool any = false;
#pragma unroll
    for (int r = 0; r < 8; ++r) { a[r] = jj[r] < ee[r]; any = any || a[r]; }
    if (!any) break;
    int si[8];
#pragma unroll
    for (int r = 0; r < 8; ++r) si[r] = colv[a[r] ? jj[r] : 0];
    ushort2 u[8];
#pragma unroll
    for (int r = 0; r < 8; ++r) u[r] = s2[(size_t)si[r] * 64 + l];
    float wt[8];
#pragma unroll
    for (int r = 0; r < 8; ++r) {
      if (sscale) wt[r] = a[r] ? sscale[si[r]] : 0.f;
      else        wt[r] = a[r] ? 1.f : 0.f;
    }
#pragma unroll
    for (int r = 0; r < 8; ++r) {
      ax[r] += bf2f(u[r].x) * wt[r];
      ay[r] += bf2f(u[r].y) * wt[r];
      jj[r] += a[r];
    }
  }

  float2 bb = {0.f, 0.f}, gg = {0.f, 0.f}, eb = {0.f, 0.f};
  if (LNEPI) {
    bb = reinterpret_cast<const float2*>(lnb)[l];
    gg = reinterpret_cast<const float2*>(lng)[l];
    eb = reinterpret_cast<const float2*>(lnbe)[l];
  }
#pragma unroll
  for (int r = 0; r < 8; ++r) {
    int row = row0 + r;
    if (row >= n) continue;
    float sc = dscale ? dscale[row] : 1.0f;
    if (LNEPI == 0) {
      ushort2 o; o.x = f2bf(ax[r] * sc); o.y = f2bf(ay[r] * sc);
      reinterpret_cast<ushort2*>(outp)[(size_t)row * 64 + l] = o;
    } else {
      float x0 = fmaxf(ax[r] * sc + bb.x, 0.f);
      float x1 = fmaxf(ay[r] * sc + bb.y, 0.f);
      float sum = waveReduceSum(x0 + x1);
      float sq  = waveReduceSum(x0 * x0 + x1 * x1);
      float mean = sum * (1.0f / HD);
      float var = sq * (1.0f / HD) - mean * mean;
      float rstd = rsqrtf(var + LN_EPS);
      float o0 = (x0 - mean) * rstd * gg.x + eb.x;
      float o1 = (x1 - mean) * rstd * gg.y + eb.y;
      if (LNEPI == 1) {
        ushort2 o; o.x = f2bf(o0); o.y = f2bf(o1);
        reinterpret_cast<ushort2*>(outp)[(size_t)row * 64 + l] = o;
      } else {
        float2 o; o.x = o0; o.y = o1;
        reinterpret_cast<float2*>(outp)[(size_t)row * 64 + l] = o;
      }
    }
  }
}

// ---------------- fused MFMA GEMM1 + bias + relu + LN + GEMM2 (BM=64, unioned LDS) ----------------
__global__ __launch_bounds__(256, 4) void k_fused_gemm_mfma(
    const unsigned short* __restrict__ in,
    const unsigned short* __restrict__ W1f, const float* __restrict__ b1,
    const float* __restrict__ g1, const float* __restrict__ be1,
    const unsigned short* __restrict__ W2f, const float* __restrict__ os,
    unsigned short* __restrict__ out, int n) {
  __shared__ __align__(16) unsigned short Sl[BM * PT];  // phase1: X 64x128; phase2: T 64x256
  __shared__ float red[4][BM], redq[4][BM];
  __shared__ float smean[BM], srstd[BM];
  int tid = threadIdx.x;
  int w = tid >> 6, l = tid & 63;
  int row0 = blockIdx.x * BM;

  // stage X: 64 rows x 128 bf16; each thread: 1 row-segment of 32 elems (4 x 16B)
  {
    int r = tid >> 2, seg = tid & 3;
    int row = row0 + r;
    s8v v0 = {}, v1 = {}, v2 = {}, v3 = {};
    if (row < n) {
      const s8v* src = reinterpret_cast<const s8v*>(in + (size_t)row * HD + seg * 32);
      v0 = src[0]; v1 = src[1]; v2 = src[2]; v3 = src[3];
    }
    unsigned short* dst = &Sl[r * PT + seg * 32];
    *reinterpret_cast<s8v*>(dst) = v0;
    *reinterpret_cast<s8v*>(dst + 8) = v1;
    *reinterpret_cast<s8v*>(dst + 16) = v2;
    *reinterpret_cast<s8v*>(dst + 24) = v3;
  }
  __syncthreads();

  // ---- GEMM1: [64x128] @ [128x256]; wave w covers cols w*64..w*64+63 ----
  f4v zz = {0.f, 0.f, 0.f, 0.f};
  f4v acc1[4][4];
#pragma unroll
  for (int rt = 0; rt < 4; ++rt)
#pragma unroll
    for (int c = 0; c < 4; ++c) acc1[rt][c] = zz;

#pragma unroll
  for (int kt = 0; kt < 4; ++kt) {
    s8v a[4];
#pragma unroll
    for (int rt = 0; rt < 4; ++rt)
      a[rt] = *reinterpret_cast<const s8v*>(&Sl[(rt * 16 + (l & 15)) * PT + kt * 32 + (l >> 4) * 8]);
#pragma unroll
    for (int c = 0; c < 4; ++c) {
      int ct = w * 4 + c;
      s8v bf = *reinterpret_cast<const s8v*>(&W1f[((size_t)(ct * 4 + kt) * 64 + l) * 8]);
#pragma unroll
      for (int rt = 0; rt < 4; ++rt)
        acc1[rt][c] = __builtin_amdgcn_mfma_f32_16x16x32_bf16(a[rt], bf, acc1[rt][c], 0, 0, 0);
    }
  }

  // bias + relu (D layout: col = ct*16 + (l&15), row = rt*16 + (l>>4)*4 + r)
  float b1c[4], g1c[4], e1c[4];
#pragma unroll
  for (int c = 0; c < 4; ++c) {
    int col = w * 64 + c * 16 + (l & 15);
    b1c[c] = b1[col]; g1c[c] = g1[col]; e1c[c] = be1[col];
  }
#pragma unroll
  for (int rt = 0; rt < 4; ++rt)
#pragma unroll
    for (int c = 0; c < 4; ++c)
#pragma unroll
      for (int r = 0; r < 4; ++r)
        acc1[rt][c][r] = fmaxf(acc1[rt][c][r] + b1c[c], 0.f);

  // LN stats
#pragma unroll
  for (int rt = 0; rt < 4; ++rt)
#pragma unroll
    for (int r = 0; r < 4; ++r) {
      float s = acc1[rt][0][r] + acc1[rt][1][r] + acc1[rt][2][r] + acc1[rt][3][r];
      float q = acc1[rt][0][r] * acc1[rt][0][r] + acc1[rt][1][r] * acc1[rt][1][r] +
                acc1[rt][2][r] * acc1[rt][2][r] + acc1[rt][3][r] * acc1[rt][3][r];
#pragma unroll
      for (int off = 1; off <= 8; off <<= 1) { s += __shfl_xor(s, off); q += __shfl_xor(q, off); }
      if ((l & 15) == 0) {
        int row = rt * 16 + (l >> 4) * 4 + r;
        red[w][row] = s; redq[w][row] = q;
      }
    }
  __syncthreads();
  if (tid < BM) {
    float S = red[0][tid] + red[1][tid] + red[2][tid] + red[3][tid];
    float Q = redq[0][tid] + redq[1][tid] + redq[2][tid] + redq[3][tid];
    float mean = S * (1.0f / HD2);
    float var = Q * (1.0f / HD2) - mean * mean;
    smean[tid] = mean;
    srstd[tid] = rsqrtf(var + LN_EPS);
  }
  __syncthreads();   // also: all X reads complete -> Sl reusable as T

  // apply LN, write normalized tile to Sl (bf16)
#pragma unroll
  for (int rt = 0; rt < 4; ++rt)
#pragma unroll
    for (int c = 0; c < 4; ++c)
#pragma unroll
      for (int r = 0; r < 4; ++r) {
        int row = rt * 16 + (l >> 4) * 4 + r;
        int col = w * 64 + c * 16 + (l & 15);
        float t = (acc1[rt][c][r] - smean[row]) * srstd[row] * g1c[c] + e1c[c];
        Sl[row * PT + col] = f2bf(t);
      }
  __syncthreads();

  // ---- GEMM2: [64x256] @ [256x128]; wave w covers cols w*32..w*32+31 ----
  f4v acc2[4][2];
#pragma unroll
  for (int rt = 0; rt < 4; ++rt)
#pragma unroll
    for (int c = 0; c < 2; ++c) acc2[rt][c] = zz;

#pragma unroll
  for (int kt = 0; kt < 8; ++kt) {
    s8v a[4];
#pragma unroll
    for (int rt = 0; rt < 4; ++rt)
      a[rt] = *reinterpret_cast<const s8v*>(&Sl[(rt * 16 + (l & 15)) * PT + kt * 32 + (l >> 4) * 8]);
#pragma unroll
    for (int c = 0; c < 2; ++c) {
      int ct2 = w * 2 + c;
      s8v bf = *reinterpret_cast<const s8v*>(&W2f[((size_t)(ct2 * 8 + kt) * 64 + l) * 8]);
#pragma unroll
      for (int rt = 0; rt < 4; ++rt)
        acc2[rt][c] = __builtin_amdgcn_mfma_f32_16x16x32_bf16(a[rt], bf, acc2[rt][c], 0, 0, 0);
    }
  }

  // store (optionally row-scaled), bf16
#pragma unroll
  for (int rt = 0; rt < 4; ++rt)
#pragma unroll
    for (int r = 0; r < 4; ++r) {
      int row = row0 + rt * 16 + (l >> 4) * 4 + r;
      if (row < n) {
        float sc = os ? os[row] : 1.0f;
#pragma unroll
        for (int c = 0; c < 2; ++c)
          out[(size_t)row * HD + (w * 2 + c) * 16 + (l & 15)] = f2bf(acc2[rt][c][r] * sc);
      }
    }
}

// Per-node 3-key attention + LN. q from bf16 emb; x1,x2 bf16; x3 f32 (in-place with out ok).
__global__ __launch_bounds__(256) void k_fuse(
    const unsigned short* __restrict__ embq, const unsigned short* __restrict__ x1,
    const unsigned short* __restrict__ x2, const float* __restrict__ x3,
    const float* __restrict__ g, const float* __restrict__ be,
    float* __restrict__ out, int n) {
  int tid = threadIdx.x;
  int row = blockIdx.x * 4 + (tid >> 6);
  if (row >= n) return;
  int l = tid & 63;
  size_t base = (size_t)row * 64 + l;
  ushort2 uq = reinterpret_cast<const ushort2*>(embq)[base];
  ushort2 u1 = reinterpret_cast<const ushort2*>(x1)[base];
  ushort2 u2 = reinterpret_cast<const ushort2*>(x2)[base];
  float2 q = make_float2(bf2f(uq.x), bf2f(uq.y));
  float2 a = make_float2(bf2f(u1.x), bf2f(u1.y));
  float2 b = make_float2(bf2f(u2.x), bf2f(u2.y));
  float2 c = reinterpret_cast<const float2*>(x3)[base];
  float d1 = waveReduceSum(q.x * a.x + q.y * a.y);
  float d2 = waveReduceSum(q.x * b.x + q.y * b.y);
  float d3 = waveReduceSum(q.x * c.x + q.y * c.y);
  const float is = 0.088388347648318447f; // 1/sqrt(128)
  float s1 = d1 * is, s2 = d2 * is, s3 = d3 * is;
  float m = fmaxf(s1, fmaxf(s2, s3));
  float p1 = expf(s1 - m), p2 = expf(s2 - m), p3 = expf(s3 - m);
  float den = 1.0f / (p1 + p2 + p3);
  p1 *= den; p2 *= den; p3 *= den;
  float ox = p1 * a.x + p2 * b.x + p3 * c.x;
  float oy = p1 * a.y + p2 * b.y + p3 * c.y;
  float sum = waveReduceSum(ox + oy);
  float sq  = waveReduceSum(ox * ox + oy * oy);
  float mean = sum * (1.0f / HD);
  float var = sq * (1.0f / HD) - mean * mean;
  float rstd = rsqrtf(var + LN_EPS);
  float2 gg = reinterpret_cast<const float2*>(g)[l];
  float2 bb = reinterpret_cast<const float2*>(be)[l];
  float2 o;
  o.x = (ox - mean) * rstd * gg.x + bb.x;
  o.y = (oy - mean) * rstd * gg.y + bb.y;
  reinterpret_cast<float2*>(out)[base] = o;
}

extern "C" void kernel_launch(void* const* d_in, const int* in_sizes, int n_in,
                              void* d_out, int out_size, void* d_ws, size_t ws_size,
                              hipStream_t stream) {
  (void)n_in; (void)out_size; (void)ws_size;
  const float* emb  = (const float*)d_in[0];
  const int* e_soc  = (const int*)d_in[1];
  const int* e_dif  = (const int*)d_in[2];
  const int* e_hyp  = (const int*)d_in[3];
  const float* fuse_g = (const float*)d_in[4];
  const float* fuse_b = (const float*)d_in[5];
  const int N  = in_sizes[0] / HD;
  const int E1 = in_sizes[1] / 2;
  const int E2 = in_sizes[2] / 2;
  const int E3 = in_sizes[3] / 2;
  float* dout = (float*)d_out;

  // ---- workspace carve-up (~135 MB) ----
  char* wsb = (char*)d_ws;
  size_t o = 0;
  auto alloc = [&](size_t bytes) { void* p = wsb + o; o = (o + bytes + 15) & ~(size_t)15; return p; };
  int* degb = (int*)alloc((size_t)4 * N * 4);   // 4 contiguous degree arrays
  int* curb = (int*)alloc((size_t)4 * N * 4);
  int* offb = (int*)alloc((size_t)4 * N * 4);
  int* bsum4  = (int*)alloc(4 * 1024 * 4);
  int* bbase4 = (int*)alloc(4 * 1024 * 4);
  int* col_soc = (int*)alloc((size_t)E1 * 4);
  int* col_dif = (int*)alloc((size_t)E2 * 4);
  int* col_hn  = (int*)alloc((size_t)E3 * 4);
  int* col_he  = (int*)alloc((size_t)E3 * 4);
  float* dsoc = (float*)alloc((size_t)N * 4);
  float* ddif = (float*)alloc((size_t)N * 4);
  float* Dinv = (float*)alloc((size_t)N * 4);
  float* Binv = (float*)alloc((size_t)N * 4);
  unsigned short* Wf1 = (unsigned short*)alloc((size_t)HD * HD2 * 2);
  unsigned short* Wf2 = (unsigned short*)alloc((size_t)HD2 * HD * 2);
  unsigned short* emb_bf = (unsigned short*)alloc((size_t)N * HD * 2);
  unsigned short* A_bf   = (unsigned short*)alloc((size_t)N * HD * 2);
  unsigned short* B_bf   = (unsigned short*)alloc((size_t)N * HD * 2);
  unsigned short* X1     = (unsigned short*)alloc((size_t)N * HD * 2);
  unsigned short* X2     = (unsigned short*)alloc((size_t)N * HD * 2);

  int* deg_soc = degb,      *deg_dif = degb + N, *deg_hn = degb + 2 * (size_t)N, *deg_he = degb + 3 * (size_t)N;
  int* cur_soc = curb,      *cur_dif = curb + N, *cur_hn = curb + 2 * (size_t)N, *cur_he = curb + 3 * (size_t)N;
  int* off_soc = offb,      *off_dif = offb + N, *off_hn = offb + 2 * (size_t)N, *off_he = offb + 3 * (size_t)N;

  const int NB = (N + 255) / 256;
  int gN   = (N + 255) / 256;
  int gRow = (N + 3) / 4;
  int g32  = (N + 31) / 32;
  int gG   = (N + BM - 1) / BM;
  int Emax = max(E1, max(E2, E3));
  const int WF1_TOT = (HD2 / 16) * (HD / 32) * 64;   // 4096
  const int WF2_TOT = (HD / 16) * (HD2 / 32) * 64;   // 4096

  // ---- degrees (one pass) ----
  k_izero<<<(4 * N + 255) / 256, 256, 0, stream>>>(degb, 4 * N);
  k_icount4<<<(Emax + 255) / 256, 256, 0, stream>>>(e_soc + E1, e_dif + E2, e_hyp, e_hyp + E3,
                                                    degb, N, E1, E2, E3);
  k_norms<<<gN, 256, 0, stream>>>(deg_soc, deg_dif, deg_hn, deg_he, dsoc, ddif, Dinv, Binv, N);

  // ---- CSR offsets (batched over 4 graphs) + columns (one pass) ----
  {
    dim3 gb(NB, 4), g1(1, 4);
    k_bsum<<<gb, 256, 0, stream>>>(degb, bsum4, N);
    k_scanblk<<<g1, 1024, 0, stream>>>(bsum4, bbase4, NB);
    k_fillof<<<gb, 256, 0, stream>>>(degb, bbase4, offb, curb, N);
  }
  k_fillcol4<<<(Emax + 255) / 256, 256, 0, stream>>>(
      e_soc, e_soc + E1, cur_soc, col_soc,
      e_dif, e_dif + E2, cur_dif, col_dif,
      e_hyp + E3, e_hyp, cur_hn, col_hn,     // node -> hyperedges
      e_hyp, e_hyp + E3, cur_he, col_he,     // hyperedge -> nodes
      E1, E2, E3);

  // ---- emb -> bf16 once ----
  k_cvt<<<(N * HD / 4 + 255) / 256, 256, 0, stream>>>(emb, emb_bf, N * HD / 4);

  // ---- two GCN paths (soc -> X1, dif -> X2) ----
  for (int p = 0; p < 2; ++p) {
    float* dinv = (p == 0) ? dsoc : ddif;
    const int* off = (p == 0) ? off_soc : off_dif;
    const int* end = (p == 0) ? cur_soc : cur_dif;
    const int* col = (p == 0) ? col_soc : col_dif;
    unsigned short* Xp = (p == 0) ? X1 : X2;
    const float* W1  = (const float*)d_in[6 + p * 8 + 0];
    const float* b1  = (const float*)d_in[6 + p * 8 + 1];
    const float* g1  = (const float*)d_in[6 + p * 8 + 2];
    const float* be1 = (const float*)d_in[6 + p * 8 + 3];
    const float* W2  = (const float*)d_in[6 + p * 8 + 4];
    const float* b2  = (const float*)d_in[6 + p * 8 + 5];
    const float* g2  = (const float*)d_in[6 + p * 8 + 6];
    const float* be2 = (const float*)d_in[6 + p * 8 + 7];

    k_wfrag<<<(WF1_TOT + 255) / 256, 256, 0, stream>>>(W1, Wf1, HD / 32, HD2, WF1_TOT);
    k_wfrag<<<(WF2_TOT + 255) / 256, 256, 0, stream>>>(W2, Wf2, HD2 / 32, HD, WF2_TOT);

    // layer1 aggregation, all scales folded: A = dinv[d]*(Σ dinv[s]x[s] + dinv[d]x[d])
    k_gather8<0><<<g32, 256, 0, stream>>>(emb_bf, dinv, dinv, 2, dinv, off, end, col,
                                          nullptr, nullptr, nullptr, A_bf, N);
    k_fused_gemm_mfma<<<gG, 256, 0, stream>>>(A_bf, Wf1, b1, g1, be1, Wf2, dinv, B_bf, N);
    // layer2 aggregation + LN fused -> Xp (bf16)
    k_gather8<1><<<g32, 256, 0, stream>>>(B_bf, nullptr, nullptr, 1, dinv, off, end, col,
                                          b2, g2, be2, Xp, N);
  }

  // ---- HGNN path (hyp -> dout) ----
  {
    const float* W1  = (const float*)d_in[22 + 0];
    const float* b1  = (const float*)d_in[22 + 1];
    const float* g1  = (const float*)d_in[22 + 2];
    const float* be1 = (const float*)d_in[22 + 3];
    const float* W2  = (const float*)d_in[22 + 4];
    const float* b2  = (const float*)d_in[22 + 5];
    const float* g2  = (const float*)d_in[22 + 6];
    const float* be2 = (const float*)d_in[22 + 7];

    k_wfrag<<<(WF1_TOT + 255) / 256, 256, 0, stream>>>(W1, Wf1, HD / 32, HD2, WF1_TOT);
    k_wfrag<<<(WF2_TOT + 255) / 256, 256, 0, stream>>>(W2, Wf2, HD2 / 32, HD, WF2_TOT);

    // He = Binv * Σ_node emb ; Bv = Dinv * Σ_he He
    k_gather8<0><<<g32, 256, 0, stream>>>(emb_bf, nullptr, nullptr, 0, Binv, off_he, cur_he, col_he,
                                          nullptr, nullptr, nullptr, A_bf, N);
    k_gather8<0><<<g32, 256, 0, stream>>>(A_bf, nullptr, nullptr, 0, Dinv, off_hn, cur_hn, col_hn,
                                          nullptr, nullptr, nullptr, B_bf, N);
    k_fused_gemm_mfma<<<gG, 256, 0, stream>>>(B_bf, Wf1, b1, g1, be1, Wf2, nullptr, A_bf, N);
    k_gather8<0><<<g32, 256, 0, stream>>>(A_bf, nullptr, nullptr, 0, Binv, off_he, cur_he, col_he,
                                          nullptr, nullptr, nullptr, B_bf, N);
    // final node-aggregation + LN fused -> dout (f32)
    k_gather8<2><<<g32, 256, 0, stream>>>(B_bf, nullptr, nullptr, 0, Dinv, off_hn, cur_hn, col_hn,
                                          b2, g2, be2, dout, N);
  }

  // ---- fusion attention + LN -> d_out (in-place over X3) ----
  k_fuse<<<gRow, 256, 0, stream>>>(emb_bf, X1, X2, dout, fuse_g, fuse_b, dout, N);
}

// Round 8
// 669.857 us; speedup vs baseline: 1.1210x; 1.1210x over previous
//
#include <hip/hip_runtime.h>
#include <math.h>

#define HD   128
#define HD2  256
#define LN_EPS 1e-5f
#define BM 64
#define PT 264   // LDS pitch in bf16 elems (256 + 8 pad)

typedef __attribute__((ext_vector_type(8))) short s8v;    // 8 x bf16 (4 VGPR)
typedef __attribute__((ext_vector_type(4))) float f4v;    // MFMA acc

static __device__ __forceinline__ float waveReduceSum(float v) {
#pragma unroll
  for (int off = 32; off >= 1; off >>= 1) v += __shfl_xor(v, off);
  return v;
}

static __device__ __forceinline__ float bf2f(unsigned short u) {
  union { unsigned int i; float f; } c; c.i = ((unsigned int)u) << 16; return c.f;
}

static __device__ __forceinline__ unsigned short f2bf(float f) {
  union { float f; unsigned int i; } c; c.f = f;
  unsigned int lsb = (c.i >> 16) & 1u;
  return (unsigned short)((c.i + 0x7fffu + lsb) >> 16);
}

// ---------------- CSR build ----------------
__global__ void k_izero(int* __restrict__ p, int n) {
  int i = blockIdx.x * blockDim.x + threadIdx.x;
  if (i < n) p[i] = 0;
}

// all 4 degree counts in one pass
__global__ void k_icount4(const int* __restrict__ i0, const int* __restrict__ i1,
                          const int* __restrict__ i2, const int* __restrict__ i3,
                          int* __restrict__ degbase, int N, int e1, int e2, int e3) {
  int i = blockIdx.x * blockDim.x + threadIdx.x;
  if (i < e1) atomicAdd(&degbase[i0[i]], 1);
  if (i < e2) atomicAdd(&degbase[N + i1[i]], 1);
  if (i < e3) atomicAdd(&degbase[2 * N + i2[i]], 1);
  if (i < e3) atomicAdd(&degbase[3 * N + i3[i]], 1);
}

__global__ void k_norms(const int* __restrict__ cs, const int* __restrict__ cd,
                        const int* __restrict__ chn, const int* __restrict__ che,
                        float* __restrict__ dsoc, float* __restrict__ ddif,
                        float* __restrict__ Dinv, float* __restrict__ Binv, int n) {
  int i = blockIdx.x * blockDim.x + threadIdx.x;
  if (i >= n) return;
  dsoc[i] = rsqrtf((float)(cs[i] + 1));
  ddif[i] = rsqrtf((float)(cd[i] + 1));
  int dn = chn[i]; Dinv[i] = dn > 0 ? 1.0f / (float)dn : 0.0f;
  int bh = che[i]; Binv[i] = bh > 0 ? 1.0f / (float)bh : 0.0f;
}

// grid (NB, 4): per-graph block sums
__global__ __launch_bounds__(256) void k_bsum(const int* __restrict__ degbase,
                                              int* __restrict__ bsumbase, int n) {
  __shared__ int sh[256];
  const int* deg = degbase + (size_t)blockIdx.y * n;
  int* bsum = bsumbase + blockIdx.y * 1024;
  int t = threadIdx.x;
  int i = blockIdx.x * 256 + t;
  sh[t] = (i < n) ? deg[i] : 0;
  __syncthreads();
  for (int d = 128; d > 0; d >>= 1) { if (t < d) sh[t] += sh[t + d]; __syncthreads(); }
  if (t == 0) bsum[blockIdx.x] = sh[0];
}

// grid (1, 4)
__global__ __launch_bounds__(1024) void k_scanblk(const int* __restrict__ bsumbase,
                                                  int* __restrict__ bbasebase, int nb) {
  __shared__ int sh[1024];
  const int* bsum = bsumbase + blockIdx.y * 1024;
  int* bbase = bbasebase + blockIdx.y * 1024;
  int t = threadIdx.x;
  int v = (t < nb) ? bsum[t] : 0;
  sh[t] = v;
  __syncthreads();
  for (int d = 1; d < 1024; d <<= 1) {
    int x = (t >= d) ? sh[t - d] : 0;
    __syncthreads();
    sh[t] += x;
    __syncthreads();
  }
  if (t < nb) bbase[t] = sh[t] - v;   // exclusive
}

// grid (NB, 4)
__global__ __launch_bounds__(256) void k_fillof(const int* __restrict__ degbase,
                                                const int* __restrict__ bbasebase,
                                                int* __restrict__ offbase, int* __restrict__ curbase,
                                                int n) {
  __shared__ int sh[256];
  const int* deg = degbase + (size_t)blockIdx.y * n;
  const int* bbase = bbasebase + blockIdx.y * 1024;
  int* off = offbase + (size_t)blockIdx.y * n;
  int* cur = curbase + (size_t)blockIdx.y * n;
  int t = threadIdx.x;
  int i = blockIdx.x * 256 + t;
  int v = (i < n) ? deg[i] : 0;
  sh[t] = v;
  __syncthreads();
  for (int d = 1; d < 256; d <<= 1) {
    int x = (t >= d) ? sh[t - d] : 0;
    __syncthreads();
    sh[t] += x;
    __syncthreads();
  }
  if (i < n) { int e = bbase[blockIdx.x] + sh[t] - v; off[i] = e; cur[i] = e; }
}

// all 4 CSR column fills in one pass; nontemporal colv stores (avoid XCD L2 line bouncing)
__global__ void k_fillcol4(
    const int* __restrict__ s0, const int* __restrict__ d0, int* __restrict__ c0, int* __restrict__ v0,
    const int* __restrict__ s1, const int* __restrict__ d1, int* __restrict__ c1, int* __restrict__ v1,
    const int* __restrict__ s2, const int* __restrict__ d2, int* __restrict__ c2, int* __restrict__ v2,
    const int* __restrict__ s3, const int* __restrict__ d3, int* __restrict__ c3, int* __restrict__ v3,
    int e1, int e2, int e3) {
  int i = blockIdx.x * blockDim.x + threadIdx.x;
  if (i < e1) { int d = d0[i]; int s = atomicAdd(&c0[d], 1); __builtin_nontemporal_store(s0[i], &v0[s]); }
  if (i < e2) { int d = d1[i]; int s = atomicAdd(&c1[d], 1); __builtin_nontemporal_store(s1[i], &v1[s]); }
  if (i < e3) { int d = d2[i]; int s = atomicAdd(&c2[d], 1); __builtin_nontemporal_store(s2[i], &v2[s]); }
  if (i < e3) { int d = d3[i]; int s = atomicAdd(&c3[d], 1); __builtin_nontemporal_store(s3[i], &v3[s]); }
}

// fp32 -> bf16 bulk convert (vectorized)
__global__ void k_cvt(const float* __restrict__ in, unsigned short* __restrict__ out, int n4) {
  int i = blockIdx.x * blockDim.x + threadIdx.x;
  if (i < n4) {
    float4 v = reinterpret_cast<const float4*>(in)[i];
    ushort4 o;
    o.x = f2bf(v.x); o.y = f2bf(v.y); o.z = f2bf(v.z); o.w = f2bf(v.w);
    reinterpret_cast<ushort4*>(out)[i] = o;
  }
}

// W [K][NC] fp32 -> fragment-ordered bf16
__global__ void k_wfrag(const float* __restrict__ W, unsigned short* __restrict__ Wf,
                        int KT, int NC, int total) {
  int t = blockIdx.x * blockDim.x + threadIdx.x;
  if (t >= total) return;
  int l = t & 63;
  int rest = t >> 6;
  int kt = rest % KT, ct = rest / KT;
  int col = ct * 16 + (l & 15);
  int k0 = kt * 32 + (l >> 4) * 8;
  s8v v;
#pragma unroll
  for (int b = 0; b < 8; ++b) v[b] = (short)f2bf(W[(size_t)(k0 + b) * NC + col]);
  *reinterpret_cast<s8v*>(&Wf[(size_t)t * 8]) = v;
}

// ---------------- gather: 16 lanes/row, cooperative col-index load + shfl broadcast ----------------
// acc[d] = selfterm + sum_{j in CSR[d]} sscale[col_j] * src[col_j]   (src bf16 [n][128])
// LNEPI 0: out = bf16(acc * dscale[d])
// LNEPI 1: out = bf16( LN(relu(acc*dscale + lnb)) * lng + lnbe )
// LNEPI 2: same but f32 out
template <int LNEPI>
__global__ __launch_bounds__(256) void k_gatherw(
    const unsigned short* __restrict__ src, const float* __restrict__ sscale,
    const float* __restrict__ selfs, int selfmode, const float* __restrict__ dscale,
    const int* __restrict__ off, const int* __restrict__ endp,
    const int* __restrict__ colv,
    const float* __restrict__ lnb, const float* __restrict__ lng,
    const float* __restrict__ lnbe, void* __restrict__ outp, int n) {
  int tid = threadIdx.x;
  int l = tid & 63;
  int sub = l & 15;                      // lane within 16-lane row group
  int row = blockIdx.x * 16 + (tid >> 4);
  bool valid = row < n;
  int rowc = valid ? row : 0;
  int j0 = valid ? off[rowc] : 0;
  int j1 = valid ? endp[rowc] : 0;
  int deg = j1 - j0;
  const s8v* s8p = reinterpret_cast<const s8v*>(src);

  float acc[8];
#pragma unroll
  for (int j = 0; j < 8; ++j) acc[j] = 0.f;
  if (selfmode && valid) {
    float ss = (selfmode == 2) ? selfs[rowc] : 1.0f;
    s8v u = s8p[(size_t)rowc * 16 + sub];
#pragma unroll
    for (int j = 0; j < 8; ++j) acc[j] = bf2f((unsigned short)u[j]) * ss;
  }

  // wave-uniform max degree across the wave's 4 row-groups
  int m = deg;
  m = max(m, __shfl_xor(m, 16));
  m = max(m, __shfl_xor(m, 32));

  for (int base = 0; base < m; base += 16) {
    int cv = 0;
    if (base + sub < deg) cv = colv[j0 + base + sub];   // one coalesced index load per group
    int lim = min(m - base, 16);                        // wave-uniform
    for (int k = 0; k < lim; ++k) {
      int c = __shfl(cv, (l & 48) + k);                 // register broadcast — no addr chain
      bool act = (base + k) < deg;
      int cc = act ? c : rowc;
      float wgt = act ? (sscale ? sscale[cc] : 1.0f) : 0.0f;
      s8v u = s8p[(size_t)cc * 16 + sub];
#pragma unroll
      for (int j = 0; j < 8; ++j) acc[j] += bf2f((unsigned short)u[j]) * wgt;
    }
  }

  if (!valid) return;
  float dsc = dscale ? dscale[row] : 1.0f;
  if (LNEPI == 0) {
    s8v o;
#pragma unroll
    for (int j = 0; j < 8; ++j) o[j] = (short)f2bf(acc[j] * dsc);
    reinterpret_cast<s8v*>(outp)[(size_t)row * 16 + sub] = o;
  } else {
    const float4* b4 = reinterpret_cast<const float4*>(lnb);
    const float4* g4 = reinterpret_cast<const float4*>(lng);
    const float4* e4 = reinterpret_cast<const float4*>(lnbe);
    float4 bA = b4[sub * 2], bB = b4[sub * 2 + 1];
    float x[8];
    x[0] = fmaxf(acc[0] * dsc + bA.x, 0.f); x[1] = fmaxf(acc[1] * dsc + bA.y, 0.f);
    x[2] = fmaxf(acc[2] * dsc + bA.z, 0.f); x[3] = fmaxf(acc[3] * dsc + bA.w, 0.f);
    x[4] = fmaxf(acc[4] * dsc + bB.x, 0.f); x[5] = fmaxf(acc[5] * dsc + bB.y, 0.f);
    x[6] = fmaxf(acc[6] * dsc + bB.z, 0.f); x[7] = fmaxf(acc[7] * dsc + bB.w, 0.f);
    float s = 0.f, q = 0.f;
#pragma unroll
    for (int j = 0; j < 8; ++j) { s += x[j]; q += x[j] * x[j]; }
#pragma unroll
    for (int o2 = 1; o2 <= 8; o2 <<= 1) { s += __shfl_xor(s, o2); q += __shfl_xor(q, o2); }
    float mean = s * (1.0f / HD);
    float var = q * (1.0f / HD) - mean * mean;
    float rstd = rsqrtf(var + LN_EPS);
    float4 gA = g4[sub * 2], gB = g4[sub * 2 + 1];
    float4 eA = e4[sub * 2], eB = e4[sub * 2 + 1];
    float o[8];
    o[0] = (x[0] - mean) * rstd * gA.x + eA.x; o[1] = (x[1] - mean) * rstd * gA.y + eA.y;
    o[2] = (x[2] - mean) * rstd * gA.z + eA.z; o[3] = (x[3] - mean) * rstd * gA.w + eA.w;
    o[4] = (x[4] - mean) * rstd * gB.x + eB.x; o[5] = (x[5] - mean) * rstd * gB.y + eB.y;
    o[6] = (x[6] - mean) * rstd * gB.z + eB.z; o[7] = (x[7] - mean) * rstd * gB.w + eB.w;
    if (LNEPI == 1) {
      s8v ob;
#pragma unroll
      for (int j = 0; j < 8; ++j) ob[j] = (short)f2bf(o[j]);
      reinterpret_cast<s8v*>(outp)[(size_t)row * 16 + sub] = ob;
    } else {
      float4 o0 = make_float4(o[0], o[1], o[2], o[3]);
      float4 o1 = make_float4(o[4], o[5], o[6], o[7]);
      reinterpret_cast<float4*>(outp)[(size_t)row * 32 + sub * 2]     = o0;
      reinterpret_cast<float4*>(outp)[(size_t)row * 32 + sub * 2 + 1] = o1;
    }
  }
}

// ---------------- fused MFMA GEMM1 + bias + relu + LN + GEMM2 (BM=64, unioned LDS) ----------------
__global__ __launch_bounds__(256, 4) void k_fused_gemm_mfma(
    const unsigned short* __restrict__ in,
    const unsigned short* __restrict__ W1f, const float* __restrict__ b1,
    const float* __restrict__ g1, const float* __restrict__ be1,
    const unsigned short* __restrict__ W2f, const float* __restrict__ os,
    unsigned short* __restrict__ out, int n) {
  __shared__ __align__(16) unsigned short Sl[BM * PT];  // phase1: X 64x128; phase2: T 64x256
  __shared__ float red[4][BM], redq[4][BM];
  __shared__ float smean[BM], srstd[BM];
  int tid = threadIdx.x;
  int w = tid >> 6, l = tid & 63;
  int row0 = blockIdx.x * BM;

  // stage X: 64 rows x 128 bf16; each thread: 1 row-segment of 32 elems (4 x 16B)
  {
    int r = tid >> 2, seg = tid & 3;
    int row = row0 + r;
    s8v v0 = {}, v1 = {}, v2 = {}, v3 = {};
    if (row < n) {
      const s8v* src = reinterpret_cast<const s8v*>(in + (size_t)row * HD + seg * 32);
      v0 = src[0]; v1 = src[1]; v2 = src[2]; v3 = src[3];
    }
    unsigned short* dst = &Sl[r * PT + seg * 32];
    *reinterpret_cast<s8v*>(dst) = v0;
    *reinterpret_cast<s8v*>(dst + 8) = v1;
    *reinterpret_cast<s8v*>(dst + 16) = v2;
    *reinterpret_cast<s8v*>(dst + 24) = v3;
  }
  __syncthreads();

  // ---- GEMM1: [64x128] @ [128x256]; wave w covers cols w*64..w*64+63 ----
  f4v zz = {0.f, 0.f, 0.f, 0.f};
  f4v acc1[4][4];
#pragma unroll
  for (int rt = 0; rt < 4; ++rt)
#pragma unroll
    for (int c = 0; c < 4; ++c) acc1[rt][c] = zz;

#pragma unroll
  for (int kt = 0; kt < 4; ++kt) {
    s8v a[4];
#pragma unroll
    for (int rt = 0; rt < 4; ++rt)
      a[rt] = *reinterpret_cast<const s8v*>(&Sl[(rt * 16 + (l & 15)) * PT + kt * 32 + (l >> 4) * 8]);
#pragma unroll
    for (int c = 0; c < 4; ++c) {
      int ct = w * 4 + c;
      s8v bf = *reinterpret_cast<const s8v*>(&W1f[((size_t)(ct * 4 + kt) * 64 + l) * 8]);
#pragma unroll
      for (int rt = 0; rt < 4; ++rt)
        acc1[rt][c] = __builtin_amdgcn_mfma_f32_16x16x32_bf16(a[rt], bf, acc1[rt][c], 0, 0, 0);
    }
  }

  // bias + relu (D layout: col = ct*16 + (l&15), row = rt*16 + (l>>4)*4 + r)
  float b1c[4], g1c[4], e1c[4];
#pragma unroll
  for (int c = 0; c < 4; ++c) {
    int col = w * 64 + c * 16 + (l & 15);
    b1c[c] = b1[col]; g1c[c] = g1[col]; e1c[c] = be1[col];
  }
#pragma unroll
  for (int rt = 0; rt < 4; ++rt)
#pragma unroll
    for (int c = 0; c < 4; ++c)
#pragma unroll
      for (int r = 0; r < 4; ++r)
        acc1[rt][c][r] = fmaxf(acc1[rt][c][r] + b1c[c], 0.f);

  // LN stats
#pragma unroll
  for (int rt = 0; rt < 4; ++rt)
#pragma unroll
    for (int r = 0; r < 4; ++r) {
      float s = acc1[rt][0][r] + acc1[rt][1][r] + acc1[rt][2][r] + acc1[rt][3][r];
      float q = acc1[rt][0][r] * acc1[rt][0][r] + acc1[rt][1][r] * acc1[rt][1][r] +
                acc1[rt][2][r] * acc1[rt][2][r] + acc1[rt][3][r] * acc1[rt][3][r];
#pragma unroll
      for (int off = 1; off <= 8; off <<= 1) { s += __shfl_xor(s, off); q += __shfl_xor(q, off); }
      if ((l & 15) == 0) {
        int row = rt * 16 + (l >> 4) * 4 + r;
        red[w][row] = s; redq[w][row] = q;
      }
    }
  __syncthreads();
  if (tid < BM) {
    float S = red[0][tid] + red[1][tid] + red[2][tid] + red[3][tid];
    float Q = redq[0][tid] + redq[1][tid] + redq[2][tid] + redq[3][tid];
    float mean = S * (1.0f / HD2);
    float var = Q * (1.0f / HD2) - mean * mean;
    smean[tid] = mean;
    srstd[tid] = rsqrtf(var + LN_EPS);
  }
  __syncthreads();   // also: all X reads complete -> Sl reusable as T

  // apply LN, write normalized tile to Sl (bf16)
#pragma unroll
  for (int rt = 0; rt < 4; ++rt)
#pragma unroll
    for (int c = 0; c < 4; ++c)
#pragma unroll
      for (int r = 0; r < 4; ++r) {
        int row = rt * 16 + (l >> 4) * 4 + r;
        int col = w * 64 + c * 16 + (l & 15);
        float t = (acc1[rt][c][r] - smean[row]) * srstd[row] * g1c[c] + e1c[c];
        Sl[row * PT + col] = f2bf(t);
      }
  __syncthreads();

  // ---- GEMM2: [64x256] @ [256x128]; wave w covers cols w*32..w*32+31 ----
  f4v acc2[4][2];
#pragma unroll
  for (int rt = 0; rt < 4; ++rt)
#pragma unroll
    for (int c = 0; c < 2; ++c) acc2[rt][c] = zz;

#pragma unroll
  for (int kt = 0; kt < 8; ++kt) {
    s8v a[4];
#pragma unroll
    for (int rt = 0; rt < 4; ++rt)
      a[rt] = *reinterpret_cast<const s8v*>(&Sl[(rt * 16 + (l & 15)) * PT + kt * 32 + (l >> 4) * 8]);
#pragma unroll
    for (int c = 0; c < 2; ++c) {
      int ct2 = w * 2 + c;
      s8v bf = *reinterpret_cast<const s8v*>(&W2f[((size_t)(ct2 * 8 + kt) * 64 + l) * 8]);
#pragma unroll
      for (int rt = 0; rt < 4; ++rt)
        acc2[rt][c] = __builtin_amdgcn_mfma_f32_16x16x32_bf16(a[rt], bf, acc2[rt][c], 0, 0, 0);
    }
  }

  // store (optionally row-scaled), bf16
#pragma unroll
  for (int rt = 0; rt < 4; ++rt)
#pragma unroll
    for (int r = 0; r < 4; ++r) {
      int row = row0 + rt * 16 + (l >> 4) * 4 + r;
      if (row < n) {
        float sc = os ? os[row] : 1.0f;
#pragma unroll
        for (int c = 0; c < 2; ++c)
          out[(size_t)row * HD + (w * 2 + c) * 16 + (l & 15)] = f2bf(acc2[rt][c][r] * sc);
      }
    }
}

// Per-node 3-key attention + LN. q from bf16 emb; x1,x2 bf16; x3 f32 (in-place with out ok).
__global__ __launch_bounds__(256) void k_fuse(
    const unsigned short* __restrict__ embq, const unsigned short* __restrict__ x1,
    const unsigned short* __restrict__ x2, const float* __restrict__ x3,
    const float* __restrict__ g, const float* __restrict__ be,
    float* __restrict__ out, int n) {
  int tid = threadIdx.x;
  int row = blockIdx.x * 4 + (tid >> 6);
  if (row >= n) return;
  int l = tid & 63;
  size_t base = (size_t)row * 64 + l;
  ushort2 uq = reinterpret_cast<const ushort2*>(embq)[base];
  ushort2 u1 = reinterpret_cast<const ushort2*>(x1)[base];
  ushort2 u2 = reinterpret_cast<const ushort2*>(x2)[base];
  float2 q = make_float2(bf2f(uq.x), bf2f(uq.y));
  float2 a = make_float2(bf2f(u1.x), bf2f(u1.y));
  float2 b = make_float2(bf2f(u2.x), bf2f(u2.y));
  float2 c = reinterpret_cast<const float2*>(x3)[base];
  float d1 = waveReduceSum(q.x * a.x + q.y * a.y);
  float d2 = waveReduceSum(q.x * b.x + q.y * b.y);
  float d3 = waveReduceSum(q.x * c.x + q.y * c.y);
  const float is = 0.088388347648318447f; // 1/sqrt(128)
  float s1 = d1 * is, s2 = d2 * is, s3 = d3 * is;
  float m = fmaxf(s1, fmaxf(s2, s3));
  float p1 = expf(s1 - m), p2 = expf(s2 - m), p3 = expf(s3 - m);
  float den = 1.0f / (p1 + p2 + p3);
  p1 *= den; p2 *= den; p3 *= den;
  float ox = p1 * a.x + p2 * b.x + p3 * c.x;
  float oy = p1 * a.y + p2 * b.y + p3 * c.y;
  float sum = waveReduceSum(ox + oy);
  float sq  = waveReduceSum(ox * ox + oy * oy);
  float mean = sum * (1.0f / HD);
  float var = sq * (1.0f / HD) - mean * mean;
  float rstd = rsqrtf(var + LN_EPS);
  float2 gg = reinterpret_cast<const float2*>(g)[l];
  float2 bb = reinterpret_cast<const float2*>(be)[l];
  float2 o;
  o.x = (ox - mean) * rstd * gg.x + bb.x;
  o.y = (oy - mean) * rstd * gg.y + bb.y;
  reinterpret_cast<float2*>(out)[base] = o;
}

extern "C" void kernel_launch(void* const* d_in, const int* in_sizes, int n_in,
                              void* d_out, int out_size, void* d_ws, size_t ws_size,
                              hipStream_t stream) {
  (void)n_in; (void)out_size; (void)ws_size;
  const float* emb  = (const float*)d_in[0];
  const int* e_soc  = (const int*)d_in[1];
  const int* e_dif  = (const int*)d_in[2];
  const int* e_hyp  = (const int*)d_in[3];
  const float* fuse_g = (const float*)d_in[4];
  const float* fuse_b = (const float*)d_in[5];
  const int N  = in_sizes[0] / HD;
  const int E1 = in_sizes[1] / 2;
  const int E2 = in_sizes[2] / 2;
  const int E3 = in_sizes[3] / 2;
  float* dout = (float*)d_out;

  // ---- workspace carve-up (~135 MB) ----
  char* wsb = (char*)d_ws;
  size_t o = 0;
  auto alloc = [&](size_t bytes) { void* p = wsb + o; o = (o + bytes + 15) & ~(size_t)15; return p; };
  int* degb = (int*)alloc((size_t)4 * N * 4);   // 4 contiguous degree arrays
  int* curb = (int*)alloc((size_t)4 * N * 4);
  int* offb = (int*)alloc((size_t)4 * N * 4);
  int* bsum4  = (int*)alloc(4 * 1024 * 4);
  int* bbase4 = (int*)alloc(4 * 1024 * 4);
  int* col_soc = (int*)alloc((size_t)E1 * 4);
  int* col_dif = (int*)alloc((size_t)E2 * 4);
  int* col_hn  = (int*)alloc((size_t)E3 * 4);
  int* col_he  = (int*)alloc((size_t)E3 * 4);
  float* dsoc = (float*)alloc((size_t)N * 4);
  float* ddif = (float*)alloc((size_t)N * 4);
  float* Dinv = (float*)alloc((size_t)N * 4);
  float* Binv = (float*)alloc((size_t)N * 4);
  unsigned short* Wf1 = (unsigned short*)alloc((size_t)HD * HD2 * 2);
  unsigned short* Wf2 = (unsigned short*)alloc((size_t)HD2 * HD * 2);
  unsigned short* emb_bf = (unsigned short*)alloc((size_t)N * HD * 2);
  unsigned short* A_bf   = (unsigned short*)alloc((size_t)N * HD * 2);
  unsigned short* B_bf   = (unsigned short*)alloc((size_t)N * HD * 2);
  unsigned short* X1     = (unsigned short*)alloc((size_t)N * HD * 2);
  unsigned short* X2     = (unsigned short*)alloc((size_t)N * HD * 2);

  int* deg_soc = degb,      *deg_dif = degb + N, *deg_hn = degb + 2 * (size_t)N, *deg_he = degb + 3 * (size_t)N;
  int* cur_soc = curb,      *cur_dif = curb + N, *cur_hn = curb + 2 * (size_t)N, *cur_he = curb + 3 * (size_t)N;
  int* off_soc = offb,      *off_dif = offb + N, *off_hn = offb + 2 * (size_t)N, *off_he = offb + 3 * (size_t)N;

  const int NB = (N + 255) / 256;
  int gN   = (N + 255) / 256;
  int gRow = (N + 3) / 4;
  int g16  = (N + 15) / 16;
  int gG   = (N + BM - 1) / BM;
  int Emax = max(E1, max(E2, E3));
  const int WF1_TOT = (HD2 / 16) * (HD / 32) * 64;   // 4096
  const int WF2_TOT = (HD / 16) * (HD2 / 32) * 64;   // 4096

  // ---- degrees (one pass) ----
  k_izero<<<(4 * N + 255) / 256, 256, 0, stream>>>(degb, 4 * N);
  k_icount4<<<(Emax + 255) / 256, 256, 0, stream>>>(e_soc + E1, e_dif + E2, e_hyp, e_hyp + E3,
                                                    degb, N, E1, E2, E3);
  k_norms<<<gN, 256, 0, stream>>>(deg_soc, deg_dif, deg_hn, deg_he, dsoc, ddif, Dinv, Binv, N);

  // ---- CSR offsets (batched over 4 graphs) + columns (one pass) ----
  {
    dim3 gb(NB, 4), g1(1, 4);
    k_bsum<<<gb, 256, 0, stream>>>(degb, bsum4, N);
    k_scanblk<<<g1, 1024, 0, stream>>>(bsum4, bbase4, NB);
    k_fillof<<<gb, 256, 0, stream>>>(degb, bbase4, offb, curb, N);
  }
  k_fillcol4<<<(Emax + 255) / 256, 256, 0, stream>>>(
      e_soc, e_soc + E1, cur_soc, col_soc,
      e_dif, e_dif + E2, cur_dif, col_dif,
      e_hyp + E3, e_hyp, cur_hn, col_hn,     // node -> hyperedges
      e_hyp, e_hyp + E3, cur_he, col_he,     // hyperedge -> nodes
      E1, E2, E3);

  // ---- emb -> bf16 once ----
  k_cvt<<<(N * HD / 4 + 255) / 256, 256, 0, stream>>>(emb, emb_bf, N * HD / 4);

  // ---- two GCN paths (soc -> X1, dif -> X2) ----
  for (int p = 0; p < 2; ++p) {
    float* dinv = (p == 0) ? dsoc : ddif;
    const int* off = (p == 0) ? off_soc : off_dif;
    const int* end = (p == 0) ? cur_soc : cur_dif;
    const int* col = (p == 0) ? col_soc : col_dif;
    unsigned short* Xp = (p == 0) ? X1 : X2;
    const float* W1  = (const float*)d_in[6 + p * 8 + 0];
    const float* b1  = (const float*)d_in[6 + p * 8 + 1];
    const float* g1  = (const float*)d_in[6 + p * 8 + 2];
    const float* be1 = (const float*)d_in[6 + p * 8 + 3];
    const float* W2  = (const float*)d_in[6 + p * 8 + 4];
    const float* b2  = (const float*)d_in[6 + p * 8 + 5];
    const float* g2  = (const float*)d_in[6 + p * 8 + 6];
    const float* be2 = (const float*)d_in[6 + p * 8 + 7];

    k_wfrag<<<(WF1_TOT + 255) / 256, 256, 0, stream>>>(W1, Wf1, HD / 32, HD2, WF1_TOT);
    k_wfrag<<<(WF2_TOT + 255) / 256, 256, 0, stream>>>(W2, Wf2, HD2 / 32, HD, WF2_TOT);

    // layer1 aggregation, all scales folded: A = dinv[d]*(Σ dinv[s]x[s] + dinv[d]x[d])
    k_gatherw<0><<<g16, 256, 0, stream>>>(emb_bf, dinv, dinv, 2, dinv, off, end, col,
                                          nullptr, nullptr, nullptr, A_bf, N);
    k_fused_gemm_mfma<<<gG, 256, 0, stream>>>(A_bf, Wf1, b1, g1, be1, Wf2, dinv, B_bf, N);
    // layer2 aggregation + LN fused -> Xp (bf16)
    k_gatherw<1><<<g16, 256, 0, stream>>>(B_bf, nullptr, nullptr, 1, dinv, off, end, col,
                                          b2, g2, be2, Xp, N);
  }

  // ---- HGNN path (hyp -> dout) ----
  {
    const float* W1  = (const float*)d_in[22 + 0];
    const float* b1  = (const float*)d_in[22 + 1];
    const float* g1  = (const float*)d_in[22 + 2];
    const float* be1 = (const float*)d_in[22 + 3];
    const float* W2  = (const float*)d_in[22 + 4];
    const float* b2  = (const float*)d_in[22 + 5];
    const float* g2  = (const float*)d_in[22 + 6];
    const float* be2 = (const float*)d_in[22 + 7];

    k_wfrag<<<(WF1_TOT + 255) / 256, 256, 0, stream>>>(W1, Wf1, HD / 32, HD2, WF1_TOT);
    k_wfrag<<<(WF2_TOT + 255) / 256, 256, 0, stream>>>(W2, Wf2, HD2 / 32, HD, WF2_TOT);

    // He = Binv * Σ_node emb ; Bv = Dinv * Σ_he He
    k_gatherw<0><<<g16, 256, 0, stream>>>(emb_bf, nullptr, nullptr, 0, Binv, off_he, cur_he, col_he,
                                          nullptr, nullptr, nullptr, A_bf, N);
    k_gatherw<0><<<g16, 256, 0, stream>>>(A_bf, nullptr, nullptr, 0, Dinv, off_hn, cur_hn, col_hn,
                                          nullptr, nullptr, nullptr, B_bf, N);
    k_fused_gemm_mfma<<<gG, 256, 0, stream>>>(B_bf, Wf1, b1, g1, be1, Wf2, nullptr, A_bf, N);
    k_gatherw<0><<<g16, 256, 0, stream>>>(A_bf, nullptr, nullptr, 0, Binv, off_he, cur_he, col_he,
                                          nullptr, nullptr, nullptr, B_bf, N);
    // final node-aggregation + LN fused -> dout (f32)
    k_gatherw<2><<<g16, 256, 0, stream>>>(B_bf, nullptr, nullptr, 0, Dinv, off_hn, cur_hn, col_hn,
                                          b2, g2, be2, dout, N);
  }

  // ---- fusion attention + LN -> d_out (in-place over X3) ----
  k_fuse<<<gRow, 256, 0, stream>>>(emb_bf, X1, X2, dout, fuse_g, fuse_b, dout, N);
}

// Round 9
// 598.748 us; speedup vs baseline: 1.2541x; 1.1188x over previous
//
#include <hip/hip_runtime.h>
#include <math.h>

#define HD   128
#define HD2  256
#define LN_EPS 1e-5f
#define BM 64
#define PT 264   // LDS pitch in bf16 elems (256 + 8 pad)

typedef __attribute__((ext_vector_type(8))) short s8v;    // 8 x bf16 (4 VGPR)
typedef __attribute__((ext_vector_type(4))) float f4v;    // MFMA acc

static __device__ __forceinline__ float waveReduceSum(float v) {
#pragma unroll
  for (int off = 32; off >= 1; off >>= 1) v += __shfl_xor(v, off);
  return v;
}

static __device__ __forceinline__ float bf2f(unsigned short u) {
  union { unsigned int i; float f; } c; c.i = ((unsigned int)u) << 16; return c.f;
}

static __device__ __forceinline__ unsigned short f2bf(float f) {
  union { float f; unsigned int i; } c; c.f = f;
  unsigned int lsb = (c.i >> 16) & 1u;
  return (unsigned short)((c.i + 0x7fffu + lsb) >> 16);
}

// ---------------- CSR build ----------------
__global__ void k_izero(int* __restrict__ p, int n) {
  int i = blockIdx.x * blockDim.x + threadIdx.x;
  if (i < n) p[i] = 0;
}

// all 4 degree counts in one pass
__global__ void k_icount4(const int* __restrict__ i0, const int* __restrict__ i1,
                          const int* __restrict__ i2, const int* __restrict__ i3,
                          int* __restrict__ degbase, int N, int e1, int e2, int e3) {
  int i = blockIdx.x * blockDim.x + threadIdx.x;
  if (i < e1) atomicAdd(&degbase[i0[i]], 1);
  if (i < e2) atomicAdd(&degbase[N + i1[i]], 1);
  if (i < e3) atomicAdd(&degbase[2 * N + i2[i]], 1);
  if (i < e3) atomicAdd(&degbase[3 * N + i3[i]], 1);
}

__global__ void k_norms(const int* __restrict__ cs, const int* __restrict__ cd,
                        const int* __restrict__ chn, const int* __restrict__ che,
                        float* __restrict__ dsoc, float* __restrict__ ddif,
                        float* __restrict__ Dinv, float* __restrict__ Binv, int n) {
  int i = blockIdx.x * blockDim.x + threadIdx.x;
  if (i >= n) return;
  dsoc[i] = rsqrtf((float)(cs[i] + 1));
  ddif[i] = rsqrtf((float)(cd[i] + 1));
  int dn = chn[i]; Dinv[i] = dn > 0 ? 1.0f / (float)dn : 0.0f;
  int bh = che[i]; Binv[i] = bh > 0 ? 1.0f / (float)bh : 0.0f;
}

// grid (NB, 4): per-graph block sums
__global__ __launch_bounds__(256) void k_bsum(const int* __restrict__ degbase,
                                              int* __restrict__ bsumbase, int n) {
  __shared__ int sh[256];
  const int* deg = degbase + (size_t)blockIdx.y * n;
  int* bsum = bsumbase + blockIdx.y * 1024;
  int t = threadIdx.x;
  int i = blockIdx.x * 256 + t;
  sh[t] = (i < n) ? deg[i] : 0;
  __syncthreads();
  for (int d = 128; d > 0; d >>= 1) { if (t < d) sh[t] += sh[t + d]; __syncthreads(); }
  if (t == 0) bsum[blockIdx.x] = sh[0];
}

// grid (1, 4)
__global__ __launch_bounds__(1024) void k_scanblk(const int* __restrict__ bsumbase,
                                                  int* __restrict__ bbasebase, int nb) {
  __shared__ int sh[1024];
  const int* bsum = bsumbase + blockIdx.y * 1024;
  int* bbase = bbasebase + blockIdx.y * 1024;
  int t = threadIdx.x;
  int v = (t < nb) ? bsum[t] : 0;
  sh[t] = v;
  __syncthreads();
  for (int d = 1; d < 1024; d <<= 1) {
    int x = (t >= d) ? sh[t - d] : 0;
    __syncthreads();
    sh[t] += x;
    __syncthreads();
  }
  if (t < nb) bbase[t] = sh[t] - v;   // exclusive
}

// grid (NB, 4)
__global__ __launch_bounds__(256) void k_fillof(const int* __restrict__ degbase,
                                                const int* __restrict__ bbasebase,
                                                int* __restrict__ offbase, int* __restrict__ curbase,
                                                int n) {
  __shared__ int sh[256];
  const int* deg = degbase + (size_t)blockIdx.y * n;
  const int* bbase = bbasebase + blockIdx.y * 1024;
  int* off = offbase + (size_t)blockIdx.y * n;
  int* cur = curbase + (size_t)blockIdx.y * n;
  int t = threadIdx.x;
  int i = blockIdx.x * 256 + t;
  int v = (i < n) ? deg[i] : 0;
  sh[t] = v;
  __syncthreads();
  for (int d = 1; d < 256; d <<= 1) {
    int x = (t >= d) ? sh[t - d] : 0;
    __syncthreads();
    sh[t] += x;
    __syncthreads();
  }
  if (i < n) { int e = bbase[blockIdx.x] + sh[t] - v; off[i] = e; cur[i] = e; }
}

// XCD-sliced CSR column fill: slice = blockIdx&7 (round-robin block->XCD) owns
// dst range [slice*ss, ...). All writes to a colv line come from one XCD -> L2 coalesces.
__global__ __launch_bounds__(256) void k_fillcol_sliced(
    const int* __restrict__ s0, const int* __restrict__ d0, int* __restrict__ c0, int* __restrict__ v0,
    const int* __restrict__ s1, const int* __restrict__ d1, int* __restrict__ c1, int* __restrict__ v1,
    const int* __restrict__ s2, const int* __restrict__ d2, int* __restrict__ c2, int* __restrict__ v2,
    const int* __restrict__ s3, const int* __restrict__ d3, int* __restrict__ c3, int* __restrict__ v3,
    int e1, int e2, int e3, int N) {
  int slice = blockIdx.x & 7;
  int rank  = blockIdx.x >> 3;
  int R = gridDim.x >> 3;
  int ss = (N + 7) / 8;
  int lo = slice * ss, hi = min(N, lo + ss);
  int stride = R * 256;
  int start = rank * 256 + threadIdx.x;
  for (int i = start; i < e1; i += stride) {
    int d = d0[i];
    if (d >= lo && d < hi) { int s = atomicAdd(&c0[d], 1); v0[s] = s0[i]; }
  }
  for (int i = start; i < e2; i += stride) {
    int d = d1[i];
    if (d >= lo && d < hi) { int s = atomicAdd(&c1[d], 1); v1[s] = s1[i]; }
  }
  for (int i = start; i < e3; i += stride) {
    int d = d2[i];
    if (d >= lo && d < hi) { int s = atomicAdd(&c2[d], 1); v2[s] = s2[i]; }
  }
  for (int i = start; i < e3; i += stride) {
    int d = d3[i];
    if (d >= lo && d < hi) { int s = atomicAdd(&c3[d], 1); v3[s] = s3[i]; }
  }
}

// fp32 -> bf16 bulk convert (vectorized)
__global__ void k_cvt(const float* __restrict__ in, unsigned short* __restrict__ out, int n4) {
  int i = blockIdx.x * blockDim.x + threadIdx.x;
  if (i < n4) {
    float4 v = reinterpret_cast<const float4*>(in)[i];
    ushort4 o;
    o.x = f2bf(v.x); o.y = f2bf(v.y); o.z = f2bf(v.z); o.w = f2bf(v.w);
    reinterpret_cast<ushort4*>(out)[i] = o;
  }
}

// batched fragment-transform of all 6 weight matrices in one launch.
// matrix m: even = W1 (K=128, NC=256, KT=4), odd = W2 (K=256, NC=128, KT=8). 16 blocks each.
struct WfArgs { const float* W[6]; unsigned short* Wf[6]; };
__global__ __launch_bounds__(256) void k_wfrag6(WfArgs a) {
  int which = blockIdx.x >> 4;                  // 0..5
  int t = (blockIdx.x & 15) * 256 + threadIdx.x;  // 0..4095
  const float* W = a.W[which];
  unsigned short* Wf = a.Wf[which];
  int KT = (which & 1) ? 8 : 4;
  int NC = (which & 1) ? 128 : 256;
  int l = t & 63;
  int rest = t >> 6;
  int kt = rest % KT, ct = rest / KT;
  int col = ct * 16 + (l & 15);
  int k0 = kt * 32 + (l >> 4) * 8;
  s8v v;
#pragma unroll
  for (int b = 0; b < 8; ++b) v[b] = (short)f2bf(W[(size_t)(k0 + b) * NC + col]);
  *reinterpret_cast<s8v*>(&Wf[(size_t)t * 8]) = v;
}

// ---------------- gather: 16 lanes/row, cooperative col-index load + shfl broadcast ----------------
// acc[d] = selfterm + sum_{j in CSR[d]} sscale[col_j] * src[col_j]   (src bf16 [n][128])
// LNEPI 0: out = bf16(acc * dscale[d])
// LNEPI 1: out = bf16( LN(relu(acc*dscale + lnb)) * lng + lnbe )
template <int LNEPI>
__global__ __launch_bounds__(256) void k_gatherw(
    const unsigned short* __restrict__ src, const float* __restrict__ sscale,
    const float* __restrict__ selfs, int selfmode, const float* __restrict__ dscale,
    const int* __restrict__ off, const int* __restrict__ endp,
    const int* __restrict__ colv,
    const float* __restrict__ lnb, const float* __restrict__ lng,
    const float* __restrict__ lnbe, void* __restrict__ outp, int n) {
  int tid = threadIdx.x;
  int l = tid & 63;
  int sub = l & 15;
  int row = blockIdx.x * 16 + (tid >> 4);
  bool valid = row < n;
  int rowc = valid ? row : 0;
  int j0 = valid ? off[rowc] : 0;
  int j1 = valid ? endp[rowc] : 0;
  int deg = j1 - j0;
  const s8v* s8p = reinterpret_cast<const s8v*>(src);

  float acc[8];
#pragma unroll
  for (int j = 0; j < 8; ++j) acc[j] = 0.f;
  if (selfmode && valid) {
    float ss = (selfmode == 2) ? selfs[rowc] : 1.0f;
    s8v u = s8p[(size_t)rowc * 16 + sub];
#pragma unroll
    for (int j = 0; j < 8; ++j) acc[j] = bf2f((unsigned short)u[j]) * ss;
  }

  int m = deg;
  m = max(m, __shfl_xor(m, 16));
  m = max(m, __shfl_xor(m, 32));

  for (int base = 0; base < m; base += 16) {
    int cv = 0;
    if (base + sub < deg) cv = colv[j0 + base + sub];
    int lim = min(m - base, 16);
    for (int k = 0; k < lim; ++k) {
      int c = __shfl(cv, (l & 48) + k);
      bool act = (base + k) < deg;
      int cc = act ? c : rowc;
      float wgt = act ? (sscale ? sscale[cc] : 1.0f) : 0.0f;
      s8v u = s8p[(size_t)cc * 16 + sub];
#pragma unroll
      for (int j = 0; j < 8; ++j) acc[j] += bf2f((unsigned short)u[j]) * wgt;
    }
  }

  if (!valid) return;
  float dsc = dscale ? dscale[row] : 1.0f;
  if (LNEPI == 0) {
    s8v o;
#pragma unroll
    for (int j = 0; j < 8; ++j) o[j] = (short)f2bf(acc[j] * dsc);
    reinterpret_cast<s8v*>(outp)[(size_t)row * 16 + sub] = o;
  } else {
    const float4* b4 = reinterpret_cast<const float4*>(lnb);
    const float4* g4 = reinterpret_cast<const float4*>(lng);
    const float4* e4 = reinterpret_cast<const float4*>(lnbe);
    float4 bA = b4[sub * 2], bB = b4[sub * 2 + 1];
    float x[8];
    x[0] = fmaxf(acc[0] * dsc + bA.x, 0.f); x[1] = fmaxf(acc[1] * dsc + bA.y, 0.f);
    x[2] = fmaxf(acc[2] * dsc + bA.z, 0.f); x[3] = fmaxf(acc[3] * dsc + bA.w, 0.f);
    x[4] = fmaxf(acc[4] * dsc + bB.x, 0.f); x[5] = fmaxf(acc[5] * dsc + bB.y, 0.f);
    x[6] = fmaxf(acc[6] * dsc + bB.z, 0.f); x[7] = fmaxf(acc[7] * dsc + bB.w, 0.f);
    float s = 0.f, q = 0.f;
#pragma unroll
    for (int j = 0; j < 8; ++j) { s += x[j]; q += x[j] * x[j]; }
#pragma unroll
    for (int o2 = 1; o2 <= 8; o2 <<= 1) { s += __shfl_xor(s, o2); q += __shfl_xor(q, o2); }
    float mean = s * (1.0f / HD);
    float var = q * (1.0f / HD) - mean * mean;
    float rstd = rsqrtf(var + LN_EPS);
    float4 gA = g4[sub * 2], gB = g4[sub * 2 + 1];
    float4 eA = e4[sub * 2], eB = e4[sub * 2 + 1];
    s8v ob;
    ob[0] = (short)f2bf((x[0] - mean) * rstd * gA.x + eA.x);
    ob[1] = (short)f2bf((x[1] - mean) * rstd * gA.y + eA.y);
    ob[2] = (short)f2bf((x[2] - mean) * rstd * gA.z + eA.z);
    ob[3] = (short)f2bf((x[3] - mean) * rstd * gA.w + eA.w);
    ob[4] = (short)f2bf((x[4] - mean) * rstd * gB.x + eB.x);
    ob[5] = (short)f2bf((x[5] - mean) * rstd * gB.y + eB.y);
    ob[6] = (short)f2bf((x[6] - mean) * rstd * gB.z + eB.z);
    ob[7] = (short)f2bf((x[7] - mean) * rstd * gB.w + eB.w);
    reinterpret_cast<s8v*>(outp)[(size_t)row * 16 + sub] = ob;
  }
}

// ---------------- final HGNN gather + LN + 3-key attention + LN, fused ----------------
// X3 = LN(relu(dscale*Σ src[col] + b2))*g2+be2 computed in-register, then
// attention over {X1,X2,X3} with Q=emb, then final LN -> dout (f32).
__global__ __launch_bounds__(256) void k_gather_fuse(
    const unsigned short* __restrict__ src, const float* __restrict__ dscale,
    const int* __restrict__ off, const int* __restrict__ endp, const int* __restrict__ colv,
    const float* __restrict__ lnb, const float* __restrict__ lng, const float* __restrict__ lnbe,
    const unsigned short* __restrict__ embq, const unsigned short* __restrict__ x1,
    const unsigned short* __restrict__ x2,
    const float* __restrict__ fg, const float* __restrict__ fb,
    float* __restrict__ out, int n) {
  int tid = threadIdx.x;
  int l = tid & 63;
  int sub = l & 15;
  int row = blockIdx.x * 16 + (tid >> 4);
  bool valid = row < n;
  int rowc = valid ? row : 0;
  int j0 = valid ? off[rowc] : 0;
  int j1 = valid ? endp[rowc] : 0;
  int deg = j1 - j0;
  const s8v* s8p = reinterpret_cast<const s8v*>(src);

  float acc[8];
#pragma unroll
  for (int j = 0; j < 8; ++j) acc[j] = 0.f;
  int m = deg;
  m = max(m, __shfl_xor(m, 16));
  m = max(m, __shfl_xor(m, 32));
  for (int base = 0; base < m; base += 16) {
    int cv = 0;
    if (base + sub < deg) cv = colv[j0 + base + sub];
    int lim = min(m - base, 16);
    for (int k = 0; k < lim; ++k) {
      int c = __shfl(cv, (l & 48) + k);
      bool act = (base + k) < deg;
      int cc = act ? c : rowc;
      float wgt = act ? 1.0f : 0.0f;
      s8v u = s8p[(size_t)cc * 16 + sub];
#pragma unroll
      for (int j = 0; j < 8; ++j) acc[j] += bf2f((unsigned short)u[j]) * wgt;
    }
  }
  if (!valid) return;

  // --- X3 = LN(relu(acc*dsc + b2)) * g2 + be2 ---
  float dsc = dscale[row];
  const float4* b4 = reinterpret_cast<const float4*>(lnb);
  const float4* g4 = reinterpret_cast<const float4*>(lng);
  const float4* e4 = reinterpret_cast<const float4*>(lnbe);
  float4 bA = b4[sub * 2], bB = b4[sub * 2 + 1];
  float x[8];
  x[0] = fmaxf(acc[0] * dsc + bA.x, 0.f); x[1] = fmaxf(acc[1] * dsc + bA.y, 0.f);
  x[2] = fmaxf(acc[2] * dsc + bA.z, 0.f); x[3] = fmaxf(acc[3] * dsc + bA.w, 0.f);
  x[4] = fmaxf(acc[4] * dsc + bB.x, 0.f); x[5] = fmaxf(acc[5] * dsc + bB.y, 0.f);
  x[6] = fmaxf(acc[6] * dsc + bB.z, 0.f); x[7] = fmaxf(acc[7] * dsc + bB.w, 0.f);
  float s = 0.f, q = 0.f;
#pragma unroll
  for (int j = 0; j < 8; ++j) { s += x[j]; q += x[j] * x[j]; }
#pragma unroll
  for (int o2 = 1; o2 <= 8; o2 <<= 1) { s += __shfl_xor(s, o2); q += __shfl_xor(q, o2); }
  float mean = s * (1.0f / HD);
  float var = q * (1.0f / HD) - mean * mean;
  float rstd = rsqrtf(var + LN_EPS);
  float4 gA = g4[sub * 2], gB = g4[sub * 2 + 1];
  float4 eA = e4[sub * 2], eB = e4[sub * 2 + 1];
  float c8[8];
  c8[0] = (x[0] - mean) * rstd * gA.x + eA.x; c8[1] = (x[1] - mean) * rstd * gA.y + eA.y;
  c8[2] = (x[2] - mean) * rstd * gA.z + eA.z; c8[3] = (x[3] - mean) * rstd * gA.w + eA.w;
  c8[4] = (x[4] - mean) * rstd * gB.x + eB.x; c8[5] = (x[5] - mean) * rstd * gB.y + eB.y;
  c8[6] = (x[6] - mean) * rstd * gB.z + eB.z; c8[7] = (x[7] - mean) * rstd * gB.w + eB.w;

  // --- attention (Q=emb, K=V={a,b,c}) ---
  s8v uq = reinterpret_cast<const s8v*>(embq)[(size_t)row * 16 + sub];
  s8v ua = reinterpret_cast<const s8v*>(x1)[(size_t)row * 16 + sub];
  s8v ub = reinterpret_cast<const s8v*>(x2)[(size_t)row * 16 + sub];
  float qa = 0.f, qb = 0.f, qc = 0.f;
  float af[8], bf8[8];
#pragma unroll
  for (int j = 0; j < 8; ++j) {
    float qf = bf2f((unsigned short)uq[j]);
    af[j] = bf2f((unsigned short)ua[j]);
    bf8[j] = bf2f((unsigned short)ub[j]);
    qa += qf * af[j]; qb += qf * bf8[j]; qc += qf * c8[j];
  }
#pragma unroll
  for (int o2 = 1; o2 <= 8; o2 <<= 1) {
    qa += __shfl_xor(qa, o2); qb += __shfl_xor(qb, o2); qc += __shfl_xor(qc, o2);
  }
  const float is = 0.088388347648318447f; // 1/sqrt(128)
  float s1 = qa * is, s2 = qb * is, s3 = qc * is;
  float mm = fmaxf(s1, fmaxf(s2, s3));
  float p1 = expf(s1 - mm), p2 = expf(s2 - mm), p3 = expf(s3 - mm);
  float den = 1.0f / (p1 + p2 + p3);
  p1 *= den; p2 *= den; p3 *= den;
  float ox[8];
  float s2sum = 0.f, q2sum = 0.f;
#pragma unroll
  for (int j = 0; j < 8; ++j) {
    ox[j] = p1 * af[j] + p2 * bf8[j] + p3 * c8[j];
    s2sum += ox[j]; q2sum += ox[j] * ox[j];
  }
#pragma unroll
  for (int o2 = 1; o2 <= 8; o2 <<= 1) {
    s2sum += __shfl_xor(s2sum, o2); q2sum += __shfl_xor(q2sum, o2);
  }
  float mean2 = s2sum * (1.0f / HD);
  float var2 = q2sum * (1.0f / HD) - mean2 * mean2;
  float rstd2 = rsqrtf(var2 + LN_EPS);
  const float4* fg4 = reinterpret_cast<const float4*>(fg);
  const float4* fb4 = reinterpret_cast<const float4*>(fb);
  float4 gfA = fg4[sub * 2], gfB = fg4[sub * 2 + 1];
  float4 bfA = fb4[sub * 2], bfB = fb4[sub * 2 + 1];
  float4 o0, o1;
  o0.x = (ox[0] - mean2) * rstd2 * gfA.x + bfA.x;
  o0.y = (ox[1] - mean2) * rstd2 * gfA.y + bfA.y;
  o0.z = (ox[2] - mean2) * rstd2 * gfA.z + bfA.z;
  o0.w = (ox[3] - mean2) * rstd2 * gfA.w + bfA.w;
  o1.x = (ox[4] - mean2) * rstd2 * gfB.x + bfB.x;
  o1.y = (ox[5] - mean2) * rstd2 * gfB.y + bfB.y;
  o1.z = (ox[6] - mean2) * rstd2 * gfB.z + bfB.z;
  o1.w = (ox[7] - mean2) * rstd2 * gfB.w + bfB.w;
  reinterpret_cast<float4*>(out)[(size_t)row * 32 + sub * 2]     = o0;
  reinterpret_cast<float4*>(out)[(size_t)row * 32 + sub * 2 + 1] = o1;
}

// ---------------- fused MFMA GEMM1 + bias + relu + LN + GEMM2 (BM=64, unioned LDS) ----------------
__global__ __launch_bounds__(256, 4) void k_fused_gemm_mfma(
    const unsigned short* __restrict__ in,
    const unsigned short* __restrict__ W1f, const float* __restrict__ b1,
    const float* __restrict__ g1, const float* __restrict__ be1,
    const unsigned short* __restrict__ W2f, const float* __restrict__ os,
    unsigned short* __restrict__ out, int n) {
  __shared__ __align__(16) unsigned short Sl[BM * PT];  // phase1: X 64x128; phase2: T 64x256
  __shared__ float red[4][BM], redq[4][BM];
  __shared__ float smean[BM], srstd[BM];
  int tid = threadIdx.x;
  int w = tid >> 6, l = tid & 63;
  int row0 = blockIdx.x * BM;

  {
    int r = tid >> 2, seg = tid & 3;
    int row = row0 + r;
    s8v v0 = {}, v1 = {}, v2 = {}, v3 = {};
    if (row < n) {
      const s8v* src = reinterpret_cast<const s8v*>(in + (size_t)row * HD + seg * 32);
      v0 = src[0]; v1 = src[1]; v2 = src[2]; v3 = src[3];
    }
    unsigned short* dst = &Sl[r * PT + seg * 32];
    *reinterpret_cast<s8v*>(dst) = v0;
    *reinterpret_cast<s8v*>(dst + 8) = v1;
    *reinterpret_cast<s8v*>(dst + 16) = v2;
    *reinterpret_cast<s8v*>(dst + 24) = v3;
  }
  __syncthreads();

  f4v zz = {0.f, 0.f, 0.f, 0.f};
  f4v acc1[4][4];
#pragma unroll
  for (int rt = 0; rt < 4; ++rt)
#pragma unroll
    for (int c = 0; c < 4; ++c) acc1[rt][c] = zz;

#pragma unroll
  for (int kt = 0; kt < 4; ++kt) {
    s8v a[4];
#pragma unroll
    for (int rt = 0; rt < 4; ++rt)
      a[rt] = *reinterpret_cast<const s8v*>(&Sl[(rt * 16 + (l & 15)) * PT + kt * 32 + (l >> 4) * 8]);
#pragma unroll
    for (int c = 0; c < 4; ++c) {
      int ct = w * 4 + c;
      s8v bf = *reinterpret_cast<const s8v*>(&W1f[((size_t)(ct * 4 + kt) * 64 + l) * 8]);
#pragma unroll
      for (int rt = 0; rt < 4; ++rt)
        acc1[rt][c] = __builtin_amdgcn_mfma_f32_16x16x32_bf16(a[rt], bf, acc1[rt][c], 0, 0, 0);
    }
  }

  float b1c[4], g1c[4], e1c[4];
#pragma unroll
  for (int c = 0; c < 4; ++c) {
    int col = w * 64 + c * 16 + (l & 15);
    b1c[c] = b1[col]; g1c[c] = g1[col]; e1c[c] = be1[col];
  }
#pragma unroll
  for (int rt = 0; rt < 4; ++rt)
#pragma unroll
    for (int c = 0; c < 4; ++c)
#pragma unroll
      for (int r = 0; r < 4; ++r)
        acc1[rt][c][r] = fmaxf(acc1[rt][c][r] + b1c[c], 0.f);

#pragma unroll
  for (int rt = 0; rt < 4; ++rt)
#pragma unroll
    for (int r = 0; r < 4; ++r) {
      float s = acc1[rt][0][r] + acc1[rt][1][r] + acc1[rt][2][r] + acc1[rt][3][r];
      float q = acc1[rt][0][r] * acc1[rt][0][r] + acc1[rt][1][r] * acc1[rt][1][r] +
                acc1[rt][2][r] * acc1[rt][2][r] + acc1[rt][3][r] * acc1[rt][3][r];
#pragma unroll
      for (int off = 1; off <= 8; off <<= 1) { s += __shfl_xor(s, off); q += __shfl_xor(q, off); }
      if ((l & 15) == 0) {
        int row = rt * 16 + (l >> 4) * 4 + r;
        red[w][row] = s; redq[w][row] = q;
      }
    }
  __syncthreads();
  if (tid < BM) {
    float S = red[0][tid] + red[1][tid] + red[2][tid] + red[3][tid];
    float Q = redq[0][tid] + redq[1][tid] + redq[2][tid] + redq[3][tid];
    float mean = S * (1.0f / HD2);
    float var = Q * (1.0f / HD2) - mean * mean;
    smean[tid] = mean;
    srstd[tid] = rsqrtf(var + LN_EPS);
  }
  __syncthreads();   // all X reads complete -> Sl reusable as T

#pragma unroll
  for (int rt = 0; rt < 4; ++rt)
#pragma unroll
    for (int c = 0; c < 4; ++c)
#pragma unroll
      for (int r = 0; r < 4; ++r) {
        int row = rt * 16 + (l >> 4) * 4 + r;
        int col = w * 64 + c * 16 + (l & 15);
        float t = (acc1[rt][c][r] - smean[row]) * srstd[row] * g1c[c] + e1c[c];
        Sl[row * PT + col] = f2bf(t);
      }
  __syncthreads();

  f4v acc2[4][2];
#pragma unroll
  for (int rt = 0; rt < 4; ++rt)
#pragma unroll
    for (int c = 0; c < 2; ++c) acc2[rt][c] = zz;

#pragma unroll
  for (int kt = 0; kt < 8; ++kt) {
    s8v a[4];
#pragma unroll
    for (int rt = 0; rt < 4; ++rt)
      a[rt] = *reinterpret_cast<const s8v*>(&Sl[(rt * 16 + (l & 15)) * PT + kt * 32 + (l >> 4) * 8]);
#pragma unroll
    for (int c = 0; c < 2; ++c) {
      int ct2 = w * 2 + c;
      s8v bf = *reinterpret_cast<const s8v*>(&W2f[((size_t)(ct2 * 8 + kt) * 64 + l) * 8]);
#pragma unroll
      for (int rt = 0; rt < 4; ++rt)
        acc2[rt][c] = __builtin_amdgcn_mfma_f32_16x16x32_bf16(a[rt], bf, acc2[rt][c], 0, 0, 0);
    }
  }

#pragma unroll
  for (int rt = 0; rt < 4; ++rt)
#pragma unroll
    for (int r = 0; r < 4; ++r) {
      int row = row0 + rt * 16 + (l >> 4) * 4 + r;
      if (row < n) {
        float sc = os ? os[row] : 1.0f;
#pragma unroll
        for (int c = 0; c < 2; ++c)
          out[(size_t)row * HD + (w * 2 + c) * 16 + (l & 15)] = f2bf(acc2[rt][c][r] * sc);
      }
    }
}

extern "C" void kernel_launch(void* const* d_in, const int* in_sizes, int n_in,
                              void* d_out, int out_size, void* d_ws, size_t ws_size,
                              hipStream_t stream) {
  (void)n_in; (void)out_size; (void)ws_size;
  const float* emb  = (const float*)d_in[0];
  const int* e_soc  = (const int*)d_in[1];
  const int* e_dif  = (const int*)d_in[2];
  const int* e_hyp  = (const int*)d_in[3];
  const float* fuse_g = (const float*)d_in[4];
  const float* fuse_b = (const float*)d_in[5];
  const int N  = in_sizes[0] / HD;
  const int E1 = in_sizes[1] / 2;
  const int E2 = in_sizes[2] / 2;
  const int E3 = in_sizes[3] / 2;
  float* dout = (float*)d_out;

  // ---- workspace carve-up (~140 MB) ----
  char* wsb = (char*)d_ws;
  size_t o = 0;
  auto alloc = [&](size_t bytes) { void* p = wsb + o; o = (o + bytes + 15) & ~(size_t)15; return p; };
  int* degb = (int*)alloc((size_t)4 * N * 4);
  int* curb = (int*)alloc((size_t)4 * N * 4);
  int* offb = (int*)alloc((size_t)4 * N * 4);
  int* bsum4  = (int*)alloc(4 * 1024 * 4);
  int* bbase4 = (int*)alloc(4 * 1024 * 4);
  int* col_soc = (int*)alloc((size_t)E1 * 4);
  int* col_dif = (int*)alloc((size_t)E2 * 4);
  int* col_hn  = (int*)alloc((size_t)E3 * 4);
  int* col_he  = (int*)alloc((size_t)E3 * 4);
  float* dsoc = (float*)alloc((size_t)N * 4);
  float* ddif = (float*)alloc((size_t)N * 4);
  float* Dinv = (float*)alloc((size_t)N * 4);
  float* Binv = (float*)alloc((size_t)N * 4);
  unsigned short* Wfb[6];
  for (int i = 0; i < 6; ++i) Wfb[i] = (unsigned short*)alloc((size_t)HD * HD2 * 2);
  unsigned short* emb_bf = (unsigned short*)alloc((size_t)N * HD * 2);
  unsigned short* A_bf   = (unsigned short*)alloc((size_t)N * HD * 2);
  unsigned short* B_bf   = (unsigned short*)alloc((size_t)N * HD * 2);
  unsigned short* X1     = (unsigned short*)alloc((size_t)N * HD * 2);
  unsigned short* X2     = (unsigned short*)alloc((size_t)N * HD * 2);

  int* deg_soc = degb,      *deg_dif = degb + N, *deg_hn = degb + 2 * (size_t)N, *deg_he = degb + 3 * (size_t)N;
  int* cur_soc = curb,      *cur_dif = curb + N, *cur_hn = curb + 2 * (size_t)N, *cur_he = curb + 3 * (size_t)N;
  int* off_soc = offb,      *off_dif = offb + N, *off_hn = offb + 2 * (size_t)N, *off_he = offb + 3 * (size_t)N;

  const int NB = (N + 255) / 256;
  int gN   = (N + 255) / 256;
  int g16  = (N + 15) / 16;
  int gG   = (N + BM - 1) / BM;
  int Emax = max(E1, max(E2, E3));

  // ---- degrees (one pass) ----
  k_izero<<<(4 * N + 255) / 256, 256, 0, stream>>>(degb, 4 * N);
  k_icount4<<<(Emax + 255) / 256, 256, 0, stream>>>(e_soc + E1, e_dif + E2, e_hyp, e_hyp + E3,
                                                    degb, N, E1, E2, E3);
  k_norms<<<gN, 256, 0, stream>>>(deg_soc, deg_dif, deg_hn, deg_he, dsoc, ddif, Dinv, Binv, N);

  // ---- CSR offsets (batched) + XCD-sliced column fill ----
  {
    dim3 gb(NB, 4), g1(1, 4);
    k_bsum<<<gb, 256, 0, stream>>>(degb, bsum4, N);
    k_scanblk<<<g1, 1024, 0, stream>>>(bsum4, bbase4, NB);
    k_fillof<<<gb, 256, 0, stream>>>(degb, bbase4, offb, curb, N);
  }
  k_fillcol_sliced<<<1024, 256, 0, stream>>>(
      e_soc, e_soc + E1, cur_soc, col_soc,
      e_dif, e_dif + E2, cur_dif, col_dif,
      e_hyp + E3, e_hyp, cur_hn, col_hn,     // node -> hyperedges
      e_hyp, e_hyp + E3, cur_he, col_he,     // hyperedge -> nodes
      E1, E2, E3, N);

  // ---- emb -> bf16 + all 6 weight fragments (one launch) ----
  k_cvt<<<(N * HD / 4 + 255) / 256, 256, 0, stream>>>(emb, emb_bf, N * HD / 4);
  {
    WfArgs wa;
    for (int p = 0; p < 3; ++p) {
      wa.W[2 * p]     = (const float*)d_in[6 + p * 8 + 0];
      wa.W[2 * p + 1] = (const float*)d_in[6 + p * 8 + 4];
      wa.Wf[2 * p]     = Wfb[2 * p];
      wa.Wf[2 * p + 1] = Wfb[2 * p + 1];
    }
    k_wfrag6<<<96, 256, 0, stream>>>(wa);
  }

  // ---- two GCN paths (soc -> X1, dif -> X2) ----
  for (int p = 0; p < 2; ++p) {
    float* dinv = (p == 0) ? dsoc : ddif;
    const int* off = (p == 0) ? off_soc : off_dif;
    const int* end = (p == 0) ? cur_soc : cur_dif;
    const int* col = (p == 0) ? col_soc : col_dif;
    unsigned short* Xp = (p == 0) ? X1 : X2;
    const float* b1  = (const float*)d_in[6 + p * 8 + 1];
    const float* g1  = (const float*)d_in[6 + p * 8 + 2];
    const float* be1 = (const float*)d_in[6 + p * 8 + 3];
    const float* b2  = (const float*)d_in[6 + p * 8 + 5];
    const float* g2  = (const float*)d_in[6 + p * 8 + 6];
    const float* be2 = (const float*)d_in[6 + p * 8 + 7];

    k_gatherw<0><<<g16, 256, 0, stream>>>(emb_bf, dinv, dinv, 2, dinv, off, end, col,
                                          nullptr, nullptr, nullptr, A_bf, N);
    k_fused_gemm_mfma<<<gG, 256, 0, stream>>>(A_bf, Wfb[2 * p], b1, g1, be1, Wfb[2 * p + 1],
                                              dinv, B_bf, N);
    k_gatherw<1><<<g16, 256, 0, stream>>>(B_bf, nullptr, nullptr, 1, dinv, off, end, col,
                                          b2, g2, be2, Xp, N);
  }

  // ---- HGNN path (hyp), final gather fused with attention -> dout ----
  {
    const float* b1  = (const float*)d_in[22 + 1];
    const float* g1  = (const float*)d_in[22 + 2];
    const float* be1 = (const float*)d_in[22 + 3];
    const float* b2  = (const float*)d_in[22 + 5];
    const float* g2  = (const float*)d_in[22 + 6];
    const float* be2 = (const float*)d_in[22 + 7];

    k_gatherw<0><<<g16, 256, 0, stream>>>(emb_bf, nullptr, nullptr, 0, Binv, off_he, cur_he, col_he,
                                          nullptr, nullptr, nullptr, A_bf, N);
    k_gatherw<0><<<g16, 256, 0, stream>>>(A_bf, nullptr, nullptr, 0, Dinv, off_hn, cur_hn, col_hn,
                                          nullptr, nullptr, nullptr, B_bf, N);
    k_fused_gemm_mfma<<<gG, 256, 0, stream>>>(B_bf, Wfb[4], b1, g1, be1, Wfb[5], nullptr, A_bf, N);
    k_gatherw<0><<<g16, 256, 0, stream>>>(A_bf, nullptr, nullptr, 0, Binv, off_he, cur_he, col_he,
                                          nullptr, nullptr, nullptr, B_bf, N);
    k_gather_fuse<<<g16, 256, 0, stream>>>(B_bf, Dinv, off_hn, cur_hn, col_hn,
                                           b2, g2, be2, emb_bf, X1, X2,
                                           fuse_g, fuse_b, dout, N);
  }
}